// Round 1
// baseline (153.470 us; speedup 1.0000x reference)
//
#include <hip/hip_runtime.h>
#include <math.h>

#define B 32
#define N 1024
#define W 128
#define R 4
#define EPSC 1e-8f

// ---- ws layout (in floats) ----
#define WS_SUM   0                              // 1 float (padded to 64)
#define WS_BW    64                             // B*16*R*N = 2097152
#define WS_FW    (WS_BW + B*16*R*N)             // B*R*N = 131072
#define WS_CONT  (WS_FW + B*R*N)                // B*R*N
#define WS_COSR  (WS_CONT + B*R*N)              // B*R*N
#define WS_COSW  (WS_COSR + B*R*N)              // B*N
#define WS_WW    (WS_COSW + B*N)                // B*N

// ---- out offsets (in floats) ----
#define O_RR    0
#define O_MEM   (O_RR + B*R*W)
#define O_LINK  (O_MEM + B*N*W)
#define O_USAGE (O_LINK + B*N*N)
#define O_PREC  (O_USAGE + B*N)
#define O_NRW   (O_PREC + B*N)

// ===================== K1: cosine scores =====================
// grid B*16, block 256. Each block: 64 memory rows; wave-per-row.
__global__ void k1_scores(const float* __restrict__ mem,
                          const float* __restrict__ rkeys,
                          const float* __restrict__ wkey,
                          float* __restrict__ ws) {
    int bx = blockIdx.x;
    int b = bx >> 4;
    int n0 = (bx & 15) << 6;
    int t = threadIdx.x;
    __shared__ float keys[5][W];
    __shared__ float knorm[5];
    for (int idx = t; idx < 5 * W; idx += 256) {
        int r = idx >> 7, w = idx & 127;
        keys[r][w] = (r < 4) ? rkeys[(b * R + r) * W + w] : wkey[b * W + w];
    }
    __syncthreads();
    if (t < 5) {
        float s = 0.f;
        for (int w = 0; w < W; ++w) { float v = keys[t][w]; s += v * v; }
        knorm[t] = sqrtf(s);
    }
    __syncthreads();
    int wave = t >> 6, lane = t & 63;
    for (int it = 0; it < 16; ++it) {
        int n = n0 + it * 4 + wave;
        const float* mrow = mem + ((size_t)(b * N + n)) * W;
        float2 m2 = *reinterpret_cast<const float2*>(mrow + 2 * lane);
        float acc[6];
        acc[0] = m2.x * m2.x + m2.y * m2.y;
        #pragma unroll
        for (int r = 0; r < 5; ++r)
            acc[r + 1] = m2.x * keys[r][2 * lane] + m2.y * keys[r][2 * lane + 1];
        #pragma unroll
        for (int s = 1; s < 64; s <<= 1) {
            #pragma unroll
            for (int q = 0; q < 6; ++q) acc[q] += __shfl_xor(acc[q], s);
        }
        if (lane == 0) {
            float mn = sqrtf(acc[0]);
            #pragma unroll
            for (int r = 0; r < 4; ++r)
                ws[WS_COSR + (b * R + r) * N + n] = acc[r + 1] / fmaxf(knorm[r] * mn, EPSC);
            ws[WS_COSW + b * N + n] = acc[5] / fmaxf(knorm[4] * mn, EPSC);
        }
    }
}

// ===================== K2: softmaxes + allocation + ww =====================
// grid B, block 256.
__global__ void k2_soft(const float* __restrict__ usage,
                        const float* __restrict__ rstr,
                        const float* __restrict__ wstr,
                        const float* __restrict__ agate,
                        const float* __restrict__ wgate,
                        float* __restrict__ ws) {
    int b = blockIdx.x, t = threadIdx.x;
    __shared__ float red[256];
    __shared__ float wc[N];

    // ---- content softmaxes (strength AFTER softmax) ----
    for (int r = 0; r < R; ++r) {
        float x[4], mx = -1e30f;
        #pragma unroll
        for (int k = 0; k < 4; ++k) {
            x[k] = ws[WS_COSR + (b * R + r) * N + t + 256 * k];
            mx = fmaxf(mx, x[k]);
        }
        red[t] = mx; __syncthreads();
        for (int s = 128; s > 0; s >>= 1) { if (t < s) red[t] = fmaxf(red[t], red[t + s]); __syncthreads(); }
        mx = red[0]; __syncthreads();
        float e[4], ls = 0.f;
        #pragma unroll
        for (int k = 0; k < 4; ++k) { e[k] = expf(x[k] - mx); ls += e[k]; }
        red[t] = ls; __syncthreads();
        for (int s = 128; s > 0; s >>= 1) { if (t < s) red[t] += red[t + s]; __syncthreads(); }
        float inv = 1.f / red[0]; __syncthreads();
        float str = rstr[b * R + r];
        #pragma unroll
        for (int k = 0; k < 4; ++k)
            ws[WS_CONT + (b * R + r) * N + t + 256 * k] = e[k] * inv * str;
    }

    // ---- write softmax (strength BEFORE softmax) ----
    {
        float wsb = wstr[b];
        float x[4], mx = -1e30f;
        #pragma unroll
        for (int k = 0; k < 4; ++k) {
            x[k] = ws[WS_COSW + b * N + t + 256 * k] * wsb;
            mx = fmaxf(mx, x[k]);
        }
        red[t] = mx; __syncthreads();
        for (int s = 128; s > 0; s >>= 1) { if (t < s) red[t] = fmaxf(red[t], red[t + s]); __syncthreads(); }
        mx = red[0]; __syncthreads();
        float e[4], ls = 0.f;
        #pragma unroll
        for (int k = 0; k < 4; ++k) { e[k] = expf(x[k] - mx); ls += e[k]; }
        red[t] = ls; __syncthreads();
        for (int s = 128; s > 0; s >>= 1) { if (t < s) red[t] += red[t + s]; __syncthreads(); }
        float inv = 1.f / red[0]; __syncthreads();
        #pragma unroll
        for (int k = 0; k < 4; ++k) wc[t + 256 * k] = e[k] * inv;
    }
    __syncthreads();

    // ---- allocation: exclusive cumprod of usage (thread owns 4 consecutive) ----
    float u[4];
    #pragma unroll
    for (int k = 0; k < 4; ++k) u[k] = usage[b * N + 4 * t + k];
    float p = u[0] * u[1] * u[2] * u[3];
    red[t] = p; __syncthreads();
    float xv = p;
    for (int s = 1; s < 256; s <<= 1) {
        float y = (t >= s) ? red[t - s] : 1.f;
        __syncthreads();
        xv *= y; red[t] = xv;
        __syncthreads();
    }
    float excl = (t == 0) ? 1.f : red[t - 1];
    __syncthreads();

    float e0 = excl, e1 = e0 * u[0], e2 = e1 * u[1], e3 = e2 * u[2];
    float al[4] = { (1.f - u[0]) * e0, (1.f - u[1]) * e1, (1.f - u[2]) * e2, (1.f - u[3]) * e3 };

    float ag = agate[b], wg = wgate[b];
    float lsum = 0.f;
    #pragma unroll
    for (int k = 0; k < 4; ++k) {
        int n = 4 * t + k;
        float wcv = wc[n];
        float v = (ag * (al[k] - wcv) + wcv) * wg;
        ws[WS_WW + b * N + n] = v;
        lsum += v;
    }
    red[t] = lsum; __syncthreads();
    for (int s = 128; s > 0; s >>= 1) { if (t < s) red[t] += red[t + s]; __syncthreads(); }
    if (t == 0) atomicAdd(&ws[WS_SUM], red[0]);
}

// ===================== K3: single pass over L =====================
// grid B*16 (64-row tiles), block 256. Writes link_new, fw (full), bw partials.
__global__ void k3_link(const float* __restrict__ L,
                        const float* __restrict__ rw,
                        const float* __restrict__ prec,
                        float* __restrict__ ws,
                        float* __restrict__ out) {
    int bx = blockIdx.x;
    int b = bx >> 4;
    int tile = bx & 15;
    int i0 = tile << 6;
    int t = threadIdx.x;
    int wave = t >> 6, lane = t & 63;
    __shared__ float wwi[64];
    __shared__ float rwi[R][64];
    __shared__ float fwp[4][R][64];

    const float* wwg = ws + WS_WW + b * N;
    if (t < 64) wwi[t] = wwg[i0 + t];
    for (int idx = t; idx < R * 64; idx += 256) {
        int r = idx >> 6, i = idx & 63;
        rwi[r][i] = rw[(b * R + r) * N + i0 + i];
    }
    __syncthreads();

    int j0 = 4 * t;
    float4 wwj = *reinterpret_cast<const float4*>(wwg + j0);
    float4 pj  = *reinterpret_cast<const float4*>(prec + b * N + j0);
    float4 rwj[R];
    #pragma unroll
    for (int r = 0; r < R; ++r)
        rwj[r] = *reinterpret_cast<const float4*>(rw + (b * R + r) * N + j0);
    float4 bwa[R];
    #pragma unroll
    for (int r = 0; r < R; ++r) bwa[r] = make_float4(0.f, 0.f, 0.f, 0.f);

    const float* Lb = L + (size_t)b * N * N;
    float* outL = out + O_LINK + (size_t)b * N * N;

    for (int i = 0; i < 64; ++i) {
        size_t rowoff = (size_t)(i0 + i) * N + j0;
        float4 v = *reinterpret_cast<const float4*>(Lb + rowoff);
        float wi = wwi[i];
        float c = 1.f - wi;
        float4 o;
        o.x = (c - wwj.x) * v.x + wi * pj.x;
        o.y = (c - wwj.y) * v.y + wi * pj.y;
        o.z = (c - wwj.z) * v.z + wi * pj.z;
        o.w = (c - wwj.w) * v.w + wi * pj.w;
        *reinterpret_cast<float4*>(outL + rowoff) = o;

        float d[R];
        #pragma unroll
        for (int r = 0; r < R; ++r)
            d[r] = v.x * rwj[r].x + v.y * rwj[r].y + v.z * rwj[r].z + v.w * rwj[r].w;
        #pragma unroll
        for (int s = 1; s < 64; s <<= 1) {
            #pragma unroll
            for (int r = 0; r < R; ++r) d[r] += __shfl_xor(d[r], s);
        }
        if (lane == 0) {
            #pragma unroll
            for (int r = 0; r < R; ++r) fwp[wave][r][i] = d[r];
        }
        #pragma unroll
        for (int r = 0; r < R; ++r) {
            float q = rwi[r][i];
            bwa[r].x += q * v.x; bwa[r].y += q * v.y;
            bwa[r].z += q * v.z; bwa[r].w += q * v.w;
        }
    }
    __syncthreads();

    // fw: reduce 4 wave partials, store final (each (b,i) owned by exactly one block)
    {
        int r = t >> 6, i = t & 63;
        float s = fwp[0][r][i] + fwp[1][r][i] + fwp[2][r][i] + fwp[3][r][i];
        ws[WS_FW + (b * R + r) * N + i0 + i] = s;
    }
    // bw: per-tile partials, no atomics
    float* bwout = ws + WS_BW + ((size_t)(b * 16 + tile) * R) * N;
    #pragma unroll
    for (int r = 0; r < R; ++r)
        *reinterpret_cast<float4*>(bwout + r * N + j0) = bwa[r];
}

// ===================== K4: finalize =====================
// grid B*8 (128-row chunks), block 256.
__global__ void k4_final(const float* __restrict__ mem,
                         const float* __restrict__ usage,
                         const float* __restrict__ prec,
                         const float* __restrict__ rmodes,
                         const float* __restrict__ fgates,
                         const float* __restrict__ ev,
                         const float* __restrict__ wv,
                         float* __restrict__ ws,
                         float* __restrict__ out) {
    int bx = blockIdx.x;
    int b = bx >> 3;
    int n0 = (bx & 7) << 7;
    int t = threadIdx.x;
    __shared__ float nrw[R][128];
    __shared__ float wwl[128];
    __shared__ float rrl[2][R][W];

    // phase 1: new_rw
    for (int idx = t; idx < R * 128; idx += 256) {
        int r = idx >> 7, nl = idx & 127, n = n0 + nl;
        float bs = 0.f;
        #pragma unroll
        for (int tile = 0; tile < 16; ++tile)
            bs += ws[WS_BW + ((size_t)(b * 16 + tile) * R + r) * N + n];
        float fwv = ws[WS_FW + (b * R + r) * N + n];
        float cv  = ws[WS_CONT + (b * R + r) * N + n];
        float m0 = rmodes[(b * R + r) * 3 + 0];
        float m1 = rmodes[(b * R + r) * 3 + 1];
        float m2 = rmodes[(b * R + r) * 3 + 2];
        float v = fwv * m0 + bs * m1 + cv * m2;
        out[O_NRW + (b * R + r) * N + n] = v;
        nrw[r][nl] = v;
    }
    __syncthreads();

    // phase 2: usage_new, precedence_new
    if (t < 128) {
        int n = n0 + t;
        float ret = 1.f;
        #pragma unroll
        for (int r = 0; r < R; ++r) ret *= (1.f - fgates[b * R + r] * nrw[r][t]);
        float u = usage[b * N + n];
        float w = ws[WS_WW + b * N + n];
        out[O_USAGE + b * N + n] = (u + w - u * w) * ret;
        float S = ws[WS_SUM];
        out[O_PREC + b * N + n] = (1.f - S) * prec[b * N + n] + w;
        wwl[t] = w;
    }
    __syncthreads();

    // phase 3: memory_new + read_result partial
    int wi = t & 127, half = t >> 7;
    float er = ev[b * W + wi], wvv = wv[b * W + wi];
    float acc[R] = {0.f, 0.f, 0.f, 0.f};
    for (int k = 0; k < 64; ++k) {
        int nl = half * 64 + k;
        int n = n0 + nl;
        size_t off = ((size_t)(b * N + n)) * W + wi;
        float m = mem[off];
        float wn = wwl[nl];
        out[O_MEM + off] = m * (1.f - wn * er) + wn * wvv;
        #pragma unroll
        for (int r = 0; r < R; ++r) acc[r] += nrw[r][nl] * m;
    }
    #pragma unroll
    for (int r = 0; r < R; ++r) rrl[half][r][wi] = acc[r];
    __syncthreads();
    for (int idx = t; idx < R * W; idx += 256) {
        int r = idx >> 7, w2 = idx & 127;
        atomicAdd(&out[O_RR + (b * R + r) * W + w2], rrl[0][r][w2] + rrl[1][r][w2]);
    }
}

extern "C" void kernel_launch(void* const* d_in, const int* in_sizes, int n_in,
                              void* d_out, int out_size, void* d_ws, size_t ws_size,
                              hipStream_t stream) {
    const float* mem    = (const float*)d_in[0];
    const float* L      = (const float*)d_in[1];
    const float* usage  = (const float*)d_in[2];
    const float* prec   = (const float*)d_in[3];
    const float* rw     = (const float*)d_in[4];
    const float* rkeys  = (const float*)d_in[5];
    const float* rstr   = (const float*)d_in[6];
    const float* rmodes = (const float*)d_in[7];
    const float* wkey   = (const float*)d_in[8];
    const float* wstr   = (const float*)d_in[9];
    const float* ag     = (const float*)d_in[10];
    const float* wg     = (const float*)d_in[11];
    const float* wv     = (const float*)d_in[12];
    const float* ev     = (const float*)d_in[13];
    const float* fg     = (const float*)d_in[14];
    float* out = (float*)d_out;
    float* ws  = (float*)d_ws;

    hipMemsetAsync(ws, 0, 256, stream);                       // sum_ww
    hipMemsetAsync(out, 0, (size_t)B * R * W * sizeof(float), stream); // read_result (atomics)

    k1_scores<<<B * 16, 256, 0, stream>>>(mem, rkeys, wkey, ws);
    k2_soft<<<B, 256, 0, stream>>>(usage, rstr, wstr, ag, wg, ws);
    k3_link<<<B * 16, 256, 0, stream>>>(L, rw, prec, ws, out);
    k4_final<<<B * 8, 256, 0, stream>>>(mem, usage, prec, rmodes, fg, ev, wv, ws, out);
}